// Round 13
// baseline (66.768 us; speedup 1.0000x reference)
//
#include <hip/hip_runtime.h>
#include <hip/hip_bf16.h>
#include <hip/hip_cooperative_groups.h>

namespace cg = cooperative_groups;

// Problem constants (from reference setup_inputs)
#define RR 3
#define BB 2
#define NN 2048
#define DD 128
#define HH 4
#define HD 32
#define LEAKY 0.2f
#define LN_EPS 1e-5f
#define LOG2E 1.4426950408889634f

using f32x4  = __attribute__((ext_vector_type(4))) float;
using bf16x8 = __attribute__((ext_vector_type(8))) short;

__device__ __forceinline__ void gload_lds16(const void* g, void* l) {
    __builtin_amdgcn_global_load_lds(
        (const __attribute__((address_space(1))) unsigned*)g,
        (__attribute__((address_space(3))) unsigned*)l, 16, 0, 0);
}
__device__ __forceinline__ void gload_lds4(const void* g, void* l) {
    __builtin_amdgcn_global_load_lds(
        (const __attribute__((address_space(1))) unsigned*)g,
        (__attribute__((address_space(3))) unsigned*)l, 4, 0, 0);
}
__device__ __forceinline__ unsigned short bfb(float x) {
    return __builtin_bit_cast(unsigned short, __float2bfloat16(x));
}

// ---------------------------------------------------------------------------
// Bitmask layout (ballot-native): per row (2048 j): 8 chunks of 256 j;
// per chunk 8 words [q][half]; word bit i <-> j = chunk*256 + half*128 + 4i + q.
// Consumer (gat): bit (c>>2) of (word[c&3] >> (jc*8 + kg*2)).
// ---------------------------------------------------------------------------

// ===========================================================================
// FUSED cooperative kernel: 768 blocks x 256 threads, 3 blocks/CU.
//   Phase 1a (all blocks): ballot-compact A -> bm (4 rows per wave).
//   Phase 1b (blocks 0..383): Wh^T = W^T@H^T via bf16 MFMA -> whT, es, ed.
//   grid.sync()
//   Phase 2 (all blocks): gat pipeline (R12 structure verbatim).
//   grid.sync()
//   Phase 3 (grid-stride): finalize LayerNorm -> out.
// ===========================================================================
__global__ __launch_bounds__(256, 3) void fused_kernel(
    const float* __restrict__ H, const int* __restrict__ A,
    const float* __restrict__ W,
    const float* __restrict__ a_src, const float* __restrict__ a_dst,
    const float* __restrict__ gamma, const float* __restrict__ beta,
    float* __restrict__ out,
    float* __restrict__ es, float* __restrict__ ed,
    __hip_bfloat16* __restrict__ whT, unsigned* __restrict__ bm,
    unsigned* __restrict__ num, float* __restrict__ den)
{
    __shared__ __align__(16) short    whs[2][4][4][32][8]; // 16 KB
    __shared__ __align__(16) unsigned bms[2][4][128];      // 4 KB
    __shared__ __align__(16) float    eds[2][4][32];       // 1 KB
    __shared__ float red[4];

    const int bid = blockIdx.x;
    const int t = threadIdx.x;
    const int w = t >> 6;
    const int l = t & 63;

    // ---------------- Phase 1a: ballot compact (all blocks) ----------------
    {
        const int g = bid * 4 + w;                 // wave 0..3071
        const int4* Ap = (const int4*)A;
#pragma unroll 1
        for (int rr = 0; rr < 4; ++rr) {
            const long crow = (long)g * 4 + rr;    // flat A row 0..12287
#pragma unroll
            for (int e = 0; e < 8; ++e) {
                const long chunk = crow * 8 + e;
                const int4 v = Ap[chunk * 64 + l]; // 1KB contiguous per wave
                const unsigned long long B0 = __ballot(v.x != 0);
                const unsigned long long B1 = __ballot(v.y != 0);
                const unsigned long long B2 = __ballot(v.z != 0);
                const unsigned long long B3 = __ballot(v.w != 0);
                if (l < 8) {
                    const unsigned long long Bq =
                        (l >= 6) ? B3 : (l >= 4) ? B2 : (l >= 2) ? B1 : B0;
                    bm[chunk * 8 + l] = (l & 1) ? (unsigned)(Bq >> 32)
                                                : (unsigned)Bq;
                }
            }
        }
    }

    // ---------------- Phase 1b: wh via MFMA (blocks 0..383) ----------------
    if (bid < 384) {
        const int rbh = bid >> 4;
        const int nch = bid & 15;
        const int h = rbh & 3;
        const int b = (rbh >> 2) & 1;
        const int r = rbh >> 3;
        const int wi = r * HH + h;
        const int lr = l & 15;
        const int lg = l >> 4;

        const float* Wp = W + (long)wi * DD * HD;
        bf16x8 afr[2][4];
#pragma unroll
        for (int mt = 0; mt < 2; ++mt)
#pragma unroll
            for (int kt = 0; kt < 4; ++kt)
#pragma unroll
                for (int e = 0; e < 8; ++e)
                    afr[mt][kt][e] = (short)bfb(Wp[(kt * 32 + lg * 8 + e) * HD + mt * 16 + lr]);

        float av[2][4], dv[2][4];
#pragma unroll
        for (int mt = 0; mt < 2; ++mt)
#pragma unroll
            for (int reg = 0; reg < 4; ++reg) {
                const int f = mt * 16 + lg * 4 + reg;
                av[mt][reg] = a_src[wi * HD + f] * LOG2E;
                dv[mt][reg] = a_dst[wi * HD + f] * LOG2E;
            }

#pragma unroll
        for (int nt = 0; nt < 2; ++nt) {
            const int ncol = nch * 128 + w * 32 + nt * 16 + lr;
            const float4* hrow4 = (const float4*)(H + ((long)b * NN + ncol) * DD);
            f32x4 acc0 = {0.f, 0.f, 0.f, 0.f};
            f32x4 acc1 = {0.f, 0.f, 0.f, 0.f};
#pragma unroll
            for (int kt = 0; kt < 4; ++kt) {
                float4 h0 = hrow4[kt * 8 + lg * 2];
                float4 h1 = hrow4[kt * 8 + lg * 2 + 1];
                bf16x8 bfr;
                bfr[0] = (short)bfb(h0.x); bfr[1] = (short)bfb(h0.y);
                bfr[2] = (short)bfb(h0.z); bfr[3] = (short)bfb(h0.w);
                bfr[4] = (short)bfb(h1.x); bfr[5] = (short)bfb(h1.y);
                bfr[6] = (short)bfb(h1.z); bfr[7] = (short)bfb(h1.w);
                acc0 = __builtin_amdgcn_mfma_f32_16x16x32_bf16(afr[0][kt], bfr, acc0, 0, 0, 0);
                acc1 = __builtin_amdgcn_mfma_f32_16x16x32_bf16(afr[1][kt], bfr, acc1, 0, 0, 0);
            }
            float s = 0.f, d = 0.f;
#pragma unroll
            for (int reg = 0; reg < 4; ++reg) {
                const int f0 = lg * 4 + reg;
                const int f1 = 16 + lg * 4 + reg;
                whT[((long)rbh * HD + f0) * NN + ncol] = __float2bfloat16(acc0[reg]);
                whT[((long)rbh * HD + f1) * NN + ncol] = __float2bfloat16(acc1[reg]);
                s = fmaf(acc0[reg], av[0][reg], s);
                s = fmaf(acc1[reg], av[1][reg], s);
                d = fmaf(acc0[reg], dv[0][reg], d);
                d = fmaf(acc1[reg], dv[1][reg], d);
            }
            s += __shfl_xor(s, 16); s += __shfl_xor(s, 32);
            d += __shfl_xor(d, 16); d += __shfl_xor(d, 32);
            if (l < 16) {
                es[(long)rbh * NN + ncol] = s;
                ed[(long)rbh * NN + ncol] = d;
            }
        }
    }

    __threadfence();
    cg::this_grid().sync();
    __threadfence();
    __builtin_amdgcn_sched_barrier(0);

    // ---------------- Phase 2: gat (R12 structure) ----------------
    {
        const int lgs = (bid % 8) * 96 + bid / 8;   // XCD-chunked swizzle
        const int jh = lgs & 1;
        const int it = (lgs >> 1) & 15;
        const int h  = (lgs >> 5) & 3;
        const int b  = (lgs >> 7) & 1;
        const int r  = lgs >> 8;
        const int i0 = it << 7;
        const int row = l & 15;
        const int kg  = l >> 4;
        const int f31 = l & 31;
        const int kgr = l >> 5;

        const int rbh = (r * BB + b) * HH + h;
        const long rbNN = (long)(r * BB + b) * NN;
        const __hip_bfloat16* whTr = whT + (long)rbh * HD * NN;
        const float* edr = ed + (long)rbh * NN;
        const int jbase = jh * (NN / 2);

#define STAGEF(s, nb) do {                                                          \
        const int j0s = jbase + (s) * 128;                                          \
        const int S_ = jh * 8 + (s);                                                \
        const int woff_ = (S_ >> 1) * 8 + (S_ & 1) + w * 2;                         \
        gload_lds16(whTr + (long)f31 * NN + j0s + w * 32 + kgr * 8,                 \
                    &whs[nb][w][0][0][0]);                                          \
        gload_lds16(whTr + (long)f31 * NN + j0s + w * 32 + (2 + kgr) * 8,           \
                    &whs[nb][w][2][0][0]);                                          \
        gload_lds4(bm + (rbNN + i0 + l) * 64 + woff_, &bms[nb][w][0]);              \
        gload_lds4(bm + (rbNN + i0 + 64 + l) * 64 + woff_, &bms[nb][w][64]);        \
        if (l < 32) gload_lds4(edr + j0s + w * 32 + l, &eds[nb][w][0]);             \
    } while (0)

        STAGEF(0, 0);

        // block-wide max of ed (upper bound; cancels exactly in num/den)
        float4 m0 = ((const float4*)edr)[t * 2];
        float4 m1 = ((const float4*)edr)[t * 2 + 1];
        float mm = fmaxf(fmaxf(fmaxf(m0.x, m0.y), fmaxf(m0.z, m0.w)),
                         fmaxf(fmaxf(m1.x, m1.y), fmaxf(m1.z, m1.w)));
#pragma unroll
        for (int d = 1; d < 64; d <<= 1) mm = fmaxf(mm, __shfl_xor(mm, d));
        if (l == 0) red[w] = mm;
        __syncthreads();
        const float medf = fmaxf(fmaxf(red[0], red[1]), fmaxf(red[2], red[3]));

        const float esvA = es[(long)rbh * NN + i0 + w * 16 + row];
        const float esvB = es[(long)rbh * NN + i0 + 64 + w * 16 + row];
        const float xA = esvA + medf, xB = esvB + medf;
        const float MA = fmaxf(xA, LEAKY * xA), MB = fmaxf(xB, LEAKY * xB);
        const float uA = esvA - MA, vA = fmaf(LEAKY, esvA, -MA);
        const float uB = esvB - MB, vB = fmaf(LEAKY, esvB, -MB);

        f32x4 acc0A = {0,0,0,0}, acc1A = {0,0,0,0}, accDA = {0,0,0,0};
        f32x4 acc0B = {0,0,0,0}, acc1B = {0,0,0,0}, accDB = {0,0,0,0};
        bf16x8 ones;
#pragma unroll
        for (int i = 0; i < 8; ++i) ones[i] = (short)0x3F80;

        const int kk = kg * 2;
        const int rAi = w * 16 + row, rBi = 64 + w * 16 + row;

        for (int s = 0; s < 8; ++s) {
            const int cb = s & 1, nb = cb ^ 1;
            if (s < 7) {
                STAGEF(s + 1, nb);
                asm volatile("s_waitcnt vmcnt(5)" ::: "memory");
            } else {
                asm volatile("s_waitcnt vmcnt(0)" ::: "memory");
            }
            __builtin_amdgcn_s_barrier();
            __builtin_amdgcn_sched_barrier(0);

            unsigned wA[4], wB[4];
#pragma unroll
            for (int q = 0; q < 4; ++q) {
                wA[q] = bms[cb][q][rAi];
                wB[q] = bms[cb][q][rBi];
            }

#pragma unroll
            for (int jc = 0; jc < 4; ++jc) {
                bf16x8 b0 = *(const bf16x8*)&whs[cb][jc][kg][row][0];
                bf16x8 b1 = *(const bf16x8*)&whs[cb][jc][kg][row + 16][0];
                float4 e0 = *(const float4*)&eds[cb][jc][kg * 8];
                float4 e1 = *(const float4*)&eds[cb][jc][kg * 8 + 4];

                unsigned uAq[4], uBq[4];
#pragma unroll
                for (int q = 0; q < 4; ++q) {
                    uAq[q] = wA[q] >> (jc * 8 + kk);
                    uBq[q] = wB[q] >> (jc * 8 + kk);
                }

                float ev[8];
                ev[0] = e0.x; ev[1] = e0.y; ev[2] = e0.z; ev[3] = e0.w;
                ev[4] = e1.x; ev[5] = e1.y; ev[6] = e1.z; ev[7] = e1.w;

                bf16x8 pA, pB;
#pragma unroll
                for (int c = 0; c < 8; ++c) {
                    float pa = __builtin_amdgcn_exp2f(
                        fmaxf(uA + ev[c], fmaf(LEAKY, ev[c], vA)));
                    float pb = __builtin_amdgcn_exp2f(
                        fmaxf(uB + ev[c], fmaf(LEAKY, ev[c], vB)));
                    const int ma = ((int)(uAq[c & 3] << (31 - (c >> 2)))) >> 31;
                    const int mb = ((int)(uBq[c & 3] << (31 - (c >> 2)))) >> 31;
                    pa = __uint_as_float(__float_as_uint(pa) & (unsigned)ma);
                    pb = __uint_as_float(__float_as_uint(pb) & (unsigned)mb);
                    __hip_bfloat16 ha = __float2bfloat16(pa);
                    __hip_bfloat16 hb = __float2bfloat16(pb);
                    pA[c] = __builtin_bit_cast(short, ha);
                    pB[c] = __builtin_bit_cast(short, hb);
                }

                acc0A = __builtin_amdgcn_mfma_f32_16x16x32_bf16(pA, b0, acc0A, 0, 0, 0);
                acc1A = __builtin_amdgcn_mfma_f32_16x16x32_bf16(pA, b1, acc1A, 0, 0, 0);
                accDA = __builtin_amdgcn_mfma_f32_16x16x32_bf16(pA, ones, accDA, 0, 0, 0);
                acc0B = __builtin_amdgcn_mfma_f32_16x16x32_bf16(pB, b0, acc0B, 0, 0, 0);
                acc1B = __builtin_amdgcn_mfma_f32_16x16x32_bf16(pB, b1, acc1B, 0, 0, 0);
                accDB = __builtin_amdgcn_mfma_f32_16x16x32_bf16(pB, ones, accDB, 0, 0, 0);
            }
            __builtin_amdgcn_s_barrier();
            __builtin_amdgcn_sched_barrier(0);
        }
#undef STAGEF

        const int fcol = l & 15;
        const int pr = r * 2 + jh;
#pragma unroll
        for (int reg = 0; reg < 4; ++reg) {
            const int orow = (l >> 4) * 4 + reg;
            const long roA = (long)pr * (BB * NN) + (long)b * NN + i0 + w * 16 + orow;
            const long roB = roA + 64;
            const unsigned wa = (unsigned)bfb(acc0A[reg]) | ((unsigned)bfb(acc1A[reg]) << 16);
            const unsigned wb_ = (unsigned)bfb(acc0B[reg]) | ((unsigned)bfb(acc1B[reg]) << 16);
            num[roA * 64 + h * 16 + fcol] = wa;
            num[roB * 64 + h * 16 + fcol] = wb_;
            if (fcol == 0) {
                den[roA * HH + h] = accDA[reg];
                den[roB * HH + h] = accDB[reg];
            }
        }
    }

    __threadfence();
    cg::this_grid().sync();
    __threadfence();
    __builtin_amdgcn_sched_barrier(0);

    // ---------------- Phase 3: finalize (grid-stride) ----------------
#pragma unroll 1
    for (int g4 = bid; g4 < BB * NN / 4; g4 += 768) {
        const long row = (long)g4 * 4 + w;
        const int hh = l >> 4, cc = l & 15;
        const int c_lo = hh * 32 + cc, c_hi = c_lo + 16;
        const float hx = H[row * DD + c_lo];
        const float hy = H[row * DD + c_hi];

        float ax = 0.f, ay = 0.f;
#pragma unroll
        for (int r = 0; r < RR; ++r) {
            float dsum = 0.f, nx = 0.f, ny = 0.f;
#pragma unroll
            for (int j = 0; j < 2; ++j) {
                const long ro = (long)(r * 2 + j) * (BB * NN) + row;
                dsum += den[ro * HH + hh];
                const unsigned wv = num[ro * 64 + l];
                nx += __uint_as_float(wv << 16);
                ny += __uint_as_float(wv & 0xffff0000u);
            }
            const float inv = (dsum > 0.f) ? 1.0f / dsum : 0.0f;
            ax = fmaf(nx, inv, ax);
            ay = fmaf(ny, inv, ay);
        }
        const float x0 = hx + ax * (1.0f / RR);
        const float x1 = hy + ay * (1.0f / RR);
        float s = x0 + x1, q = x0 * x0 + x1 * x1;
#pragma unroll
        for (int m = 1; m < 64; m <<= 1) {
            s += __shfl_xor(s, m);
            q += __shfl_xor(q, m);
        }
        const float mu  = s * (1.0f / DD);
        const float var = q * (1.0f / DD) - mu * mu;
        const float inv = rsqrtf(var + LN_EPS);
        out[row * DD + c_lo] = (x0 - mu) * inv * gamma[c_lo] + beta[c_lo];
        out[row * DD + c_hi] = (x1 - mu) * inv * gamma[c_hi] + beta[c_hi];
    }
}

// ===========================================================================
// FALLBACK path: R12's three kernels (used only if cooperative capacity or
// launch fails). Proven correct at 66 us.
// ===========================================================================
__global__ __launch_bounds__(256) void prep_kernel(
    const float* __restrict__ H, const int* __restrict__ A,
    const float* __restrict__ W,
    const float* __restrict__ a_src, const float* __restrict__ a_dst,
    float* __restrict__ es, float* __restrict__ ed,
    __hip_bfloat16* __restrict__ whT, unsigned* __restrict__ bm)
{
    const int bid = blockIdx.x;
    const int t = threadIdx.x;

    if (bid >= 384) {
        const int cb = bid - 384;
        const int wv = cb * 4 + (t >> 6);
        const int lane = t & 63;
        const int4* Ap = (const int4*)A;
#pragma unroll
        for (int e = 0; e < 8; ++e) {
            const long chunk = (long)wv * 8 + e;
            const int4 v = Ap[chunk * 64 + lane];
            const unsigned long long B0 = __ballot(v.x != 0);
            const unsigned long long B1 = __ballot(v.y != 0);
            const unsigned long long B2 = __ballot(v.z != 0);
            const unsigned long long B3 = __ballot(v.w != 0);
            if (lane < 8) {
                const unsigned long long Bq =
                    (lane >= 6) ? B3 : (lane >= 4) ? B2 : (lane >= 2) ? B1 : B0;
                bm[chunk * 8 + lane] = (lane & 1) ? (unsigned)(Bq >> 32)
                                                  : (unsigned)Bq;
            }
        }
        return;
    }

    const int rbh = bid >> 4;
    const int nch = bid & 15;
    const int h = rbh & 3;
    const int b = (rbh >> 2) & 1;
    const int r = rbh >> 3;
    const int wi = r * HH + h;
    const int w  = t >> 6;
    const int l  = t & 63;
    const int lr = l & 15;
    const int lg = l >> 4;

    const float* Wp = W + (long)wi * DD * HD;
    bf16x8 afr[2][4];
#pragma unroll
    for (int mt = 0; mt < 2; ++mt)
#pragma unroll
        for (int kt = 0; kt < 4; ++kt)
#pragma unroll
            for (int e = 0; e < 8; ++e)
                afr[mt][kt][e] = (short)bfb(Wp[(kt * 32 + lg * 8 + e) * HD + mt * 16 + lr]);

    float av[2][4], dv[2][4];
#pragma unroll
    for (int mt = 0; mt < 2; ++mt)
#pragma unroll
        for (int reg = 0; reg < 4; ++reg) {
            const int f = mt * 16 + lg * 4 + reg;
            av[mt][reg] = a_src[wi * HD + f] * LOG2E;
            dv[mt][reg] = a_dst[wi * HD + f] * LOG2E;
        }

#pragma unroll
    for (int nt = 0; nt < 2; ++nt) {
        const int ncol = nch * 128 + w * 32 + nt * 16 + lr;
        const float4* hrow4 = (const float4*)(H + ((long)b * NN + ncol) * DD);
        f32x4 acc0 = {0.f, 0.f, 0.f, 0.f};
        f32x4 acc1 = {0.f, 0.f, 0.f, 0.f};
#pragma unroll
        for (int kt = 0; kt < 4; ++kt) {
            float4 h0 = hrow4[kt * 8 + lg * 2];
            float4 h1 = hrow4[kt * 8 + lg * 2 + 1];
            bf16x8 bfr;
            bfr[0] = (short)bfb(h0.x); bfr[1] = (short)bfb(h0.y);
            bfr[2] = (short)bfb(h0.z); bfr[3] = (short)bfb(h0.w);
            bfr[4] = (short)bfb(h1.x); bfr[5] = (short)bfb(h1.y);
            bfr[6] = (short)bfb(h1.z); bfr[7] = (short)bfb(h1.w);
            acc0 = __builtin_amdgcn_mfma_f32_16x16x32_bf16(afr[0][kt], bfr, acc0, 0, 0, 0);
            acc1 = __builtin_amdgcn_mfma_f32_16x16x32_bf16(afr[1][kt], bfr, acc1, 0, 0, 0);
        }
        float s = 0.f, d = 0.f;
#pragma unroll
        for (int reg = 0; reg < 4; ++reg) {
            const int f0 = lg * 4 + reg;
            const int f1 = 16 + lg * 4 + reg;
            whT[((long)rbh * HD + f0) * NN + ncol] = __float2bfloat16(acc0[reg]);
            whT[((long)rbh * HD + f1) * NN + ncol] = __float2bfloat16(acc1[reg]);
            s = fmaf(acc0[reg], av[0][reg], s);
            s = fmaf(acc1[reg], av[1][reg], s);
            d = fmaf(acc0[reg], dv[0][reg], d);
            d = fmaf(acc1[reg], dv[1][reg], d);
        }
        s += __shfl_xor(s, 16); s += __shfl_xor(s, 32);
        d += __shfl_xor(d, 16); d += __shfl_xor(d, 32);
        if (l < 16) {
            es[(long)rbh * NN + ncol] = s;
            ed[(long)rbh * NN + ncol] = d;
        }
    }
}

__global__ __launch_bounds__(256, 3) void gat_attn_kernel(
    const unsigned* __restrict__ bm, const float* __restrict__ es,
    const float* __restrict__ ed, const __hip_bfloat16* __restrict__ whT,
    unsigned* __restrict__ num, float* __restrict__ den)
{
    const int lg = ((int)blockIdx.x % 8) * 96 + (int)blockIdx.x / 8;
    const int jh = lg & 1;
    const int it = (lg >> 1) & 15;
    const int h  = (lg >> 5) & 3;
    const int b  = (lg >> 7) & 1;
    const int r  = lg >> 8;
    const int i0 = it << 7;
    const int tid = threadIdx.x;
    const int w = tid >> 6;
    const int l = tid & 63;
    const int row = l & 15;
    const int kg  = l >> 4;
    const int f31 = l & 31;
    const int kgr = l >> 5;

    __shared__ __align__(16) short    whs[2][4][4][32][8];
    __shared__ __align__(16) unsigned bms[2][4][128];
    __shared__ __align__(16) float    eds[2][4][32];
    __shared__ float red[4];

    const int rbh = (r * BB + b) * HH + h;
    const long rbNN = (long)(r * BB + b) * NN;
    const __hip_bfloat16* whTr = whT + (long)rbh * HD * NN;
    const float* edr = ed + (long)rbh * NN;
    const int jbase = jh * (NN / 2);

#define STAGE(s, nb) do {                                                           \
        const int j0s = jbase + (s) * 128;                                          \
        const int S_ = jh * 8 + (s);                                                \
        const int woff_ = (S_ >> 1) * 8 + (S_ & 1) + w * 2;                         \
        gload_lds16(whTr + (long)f31 * NN + j0s + w * 32 + kgr * 8,                 \
                    &whs[nb][w][0][0][0]);                                          \
        gload_lds16(whTr + (long)f31 * NN + j0s + w * 32 + (2 + kgr) * 8,           \
                    &whs[nb][w][2][0][0]);                                          \
        gload_lds4(bm + (rbNN + i0 + l) * 64 + woff_, &bms[nb][w][0]);              \
        gload_lds4(bm + (rbNN + i0 + 64 + l) * 64 + woff_, &bms[nb][w][64]);        \
        if (l < 32) gload_lds4(edr + j0s + w * 32 + l, &eds[nb][w][0]);             \
    } while (0)

    STAGE(0, 0);

    float4 m0 = ((const float4*)edr)[tid * 2];
    float4 m1 = ((const float4*)edr)[tid * 2 + 1];
    float mm = fmaxf(fmaxf(fmaxf(m0.x, m0.y), fmaxf(m0.z, m0.w)),
                     fmaxf(fmaxf(m1.x, m1.y), fmaxf(m1.z, m1.w)));
#pragma unroll
    for (int d = 1; d < 64; d <<= 1) mm = fmaxf(mm, __shfl_xor(mm, d));
    if (l == 0) red[w] = mm;
    __syncthreads();
    const float medf = fmaxf(fmaxf(red[0], red[1]), fmaxf(red[2], red[3]));

    const float esvA = es[(long)rbh * NN + i0 + w * 16 + row];
    const float esvB = es[(long)rbh * NN + i0 + 64 + w * 16 + row];
    const float xA = esvA + medf, xB = esvB + medf;
    const float MA = fmaxf(xA, LEAKY * xA), MB = fmaxf(xB, LEAKY * xB);
    const float uA = esvA - MA, vA = fmaf(LEAKY, esvA, -MA);
    const float uB = esvB - MB, vB = fmaf(LEAKY, esvB, -MB);

    f32x4 acc0A = {0,0,0,0}, acc1A = {0,0,0,0}, accDA = {0,0,0,0};
    f32x4 acc0B = {0,0,0,0}, acc1B = {0,0,0,0}, accDB = {0,0,0,0};
    bf16x8 ones;
#pragma unroll
    for (int i = 0; i < 8; ++i) ones[i] = (short)0x3F80;

    const int kk = kg * 2;
    const int rAi = w * 16 + row, rBi = 64 + w * 16 + row;

    for (int s = 0; s < 8; ++s) {
        const int cb = s & 1, nb = cb ^ 1;
        if (s < 7) {
            STAGE(s + 1, nb);
            asm volatile("s_waitcnt vmcnt(5)" ::: "memory");
        } else {
            asm volatile("s_waitcnt vmcnt(0)" ::: "memory");
        }
        __builtin_amdgcn_s_barrier();
        __builtin_amdgcn_sched_barrier(0);

        unsigned wA[4], wB[4];
#pragma unroll
        for (int q = 0; q < 4; ++q) {
            wA[q] = bms[cb][q][rAi];
            wB[q] = bms[cb][q][rBi];
        }

#pragma unroll
        for (int jc = 0; jc < 4; ++jc) {
            bf16x8 b0 = *(const bf16x8*)&whs[cb][jc][kg][row][0];
            bf16x8 b1 = *(const bf16x8*)&whs[cb][jc][kg][row + 16][0];
            float4 e0 = *(const float4*)&eds[cb][jc][kg * 8];
            float4 e1 = *(const float4*)&eds[cb][jc][kg * 8 + 4];

            unsigned uAq[4], uBq[4];
#pragma unroll
            for (int q = 0; q < 4; ++q) {
                uAq[q] = wA[q] >> (jc * 8 + kk);
                uBq[q] = wB[q] >> (jc * 8 + kk);
            }

            float ev[8];
            ev[0] = e0.x; ev[1] = e0.y; ev[2] = e0.z; ev[3] = e0.w;
            ev[4] = e1.x; ev[5] = e1.y; ev[6] = e1.z; ev[7] = e1.w;

            bf16x8 pA, pB;
#pragma unroll
            for (int c = 0; c < 8; ++c) {
                float pa = __builtin_amdgcn_exp2f(
                    fmaxf(uA + ev[c], fmaf(LEAKY, ev[c], vA)));
                float pb = __builtin_amdgcn_exp2f(
                    fmaxf(uB + ev[c], fmaf(LEAKY, ev[c], vB)));
                const int ma = ((int)(uAq[c & 3] << (31 - (c >> 2)))) >> 31;
                const int mb = ((int)(uBq[c & 3] << (31 - (c >> 2)))) >> 31;
                pa = __uint_as_float(__float_as_uint(pa) & (unsigned)ma);
                pb = __uint_as_float(__float_as_uint(pb) & (unsigned)mb);
                __hip_bfloat16 ha = __float2bfloat16(pa);
                __hip_bfloat16 hb = __float2bfloat16(pb);
                pA[c] = __builtin_bit_cast(short, ha);
                pB[c] = __builtin_bit_cast(short, hb);
            }

            acc0A = __builtin_amdgcn_mfma_f32_16x16x32_bf16(pA, b0, acc0A, 0, 0, 0);
            acc1A = __builtin_amdgcn_mfma_f32_16x16x32_bf16(pA, b1, acc1A, 0, 0, 0);
            accDA = __builtin_amdgcn_mfma_f32_16x16x32_bf16(pA, ones, accDA, 0, 0, 0);
            acc0B = __builtin_amdgcn_mfma_f32_16x16x32_bf16(pB, b0, acc0B, 0, 0, 0);
            acc1B = __builtin_amdgcn_mfma_f32_16x16x32_bf16(pB, b1, acc1B, 0, 0, 0);
            accDB = __builtin_amdgcn_mfma_f32_16x16x32_bf16(pB, ones, accDB, 0, 0, 0);
        }
        __builtin_amdgcn_s_barrier();
        __builtin_amdgcn_sched_barrier(0);
    }
#undef STAGE

    const int fcol = l & 15;
    const int pr = r * 2 + jh;
#pragma unroll
    for (int reg = 0; reg < 4; ++reg) {
        const int orow = (l >> 4) * 4 + reg;
        const long roA = (long)pr * (BB * NN) + (long)b * NN + i0 + w * 16 + orow;
        const long roB = roA + 64;
        const unsigned wa = (unsigned)bfb(acc0A[reg]) | ((unsigned)bfb(acc1A[reg]) << 16);
        const unsigned wb_ = (unsigned)bfb(acc0B[reg]) | ((unsigned)bfb(acc1B[reg]) << 16);
        num[roA * 64 + h * 16 + fcol] = wa;
        num[roB * 64 + h * 16 + fcol] = wb_;
        if (fcol == 0) {
            den[roA * HH + h] = accDA[reg];
            den[roB * HH + h] = accDB[reg];
        }
    }
}

__global__ __launch_bounds__(256) void finalize_kernel(
    const float* __restrict__ H, const unsigned* __restrict__ num,
    const float* __restrict__ den,
    const float* __restrict__ gamma, const float* __restrict__ beta,
    float* __restrict__ out)
{
    const int w = threadIdx.x >> 6;
    const int l = threadIdx.x & 63;
    const long row = (long)blockIdx.x * 4 + w;
    const int hh = l >> 4, cc = l & 15;
    const int c_lo = hh * 32 + cc, c_hi = c_lo + 16;
    const float hx = H[row * DD + c_lo];
    const float hy = H[row * DD + c_hi];

    float ax = 0.f, ay = 0.f;
#pragma unroll
    for (int r = 0; r < RR; ++r) {
        float dsum = 0.f, nx = 0.f, ny = 0.f;
#pragma unroll
        for (int j = 0; j < 2; ++j) {
            const long ro = (long)(r * 2 + j) * (BB * NN) + row;
            dsum += den[ro * HH + hh];
            const unsigned wv = num[ro * 64 + l];
            nx += __uint_as_float(wv << 16);
            ny += __uint_as_float(wv & 0xffff0000u);
        }
        const float inv = (dsum > 0.f) ? 1.0f / dsum : 0.0f;
        ax = fmaf(nx, inv, ax);
        ay = fmaf(ny, inv, ay);
    }
    const float x0 = hx + ax * (1.0f / RR);
    const float x1 = hy + ay * (1.0f / RR);
    float s = x0 + x1, q = x0 * x0 + x1 * x1;
#pragma unroll
    for (int m = 1; m < 64; m <<= 1) {
        s += __shfl_xor(s, m);
        q += __shfl_xor(q, m);
    }
    const float mu  = s * (1.0f / DD);
    const float var = q * (1.0f / DD) - mu * mu;
    const float inv = rsqrtf(var + LN_EPS);
    out[row * DD + c_lo] = (x0 - mu) * inv * gamma[c_lo] + beta[c_lo];
    out[row * DD + c_hi] = (x1 - mu) * inv * gamma[c_hi] + beta[c_hi];
}

// ---------------------------------------------------------------------------
extern "C" void kernel_launch(void* const* d_in, const int* in_sizes, int n_in,
                              void* d_out, int out_size, void* d_ws, size_t ws_size,
                              hipStream_t stream)
{
    const float* H      = (const float*)d_in[0];
    const int*   A      = (const int*)d_in[1];
    const float* W      = (const float*)d_in[2];
    const float* a_src  = (const float*)d_in[3];
    const float* a_dst  = (const float*)d_in[4];
    const float* gamma  = (const float*)d_in[5];
    const float* beta   = (const float*)d_in[6];
    float* out = (float*)d_out;

    // workspace carve (~13.4 MB)
    char* ws = (char*)d_ws;
    unsigned* num = (unsigned*)ws;               ws += (size_t)RR * 2 * BB * NN * 64 * 4;
    float* den = (float*)ws;                     ws += (size_t)RR * 2 * BB * NN * HH * 4;
    float* es  = (float*)ws;                     ws += (size_t)RR * BB * HH * NN * 4;
    float* ed  = (float*)ws;                     ws += (size_t)RR * BB * HH * NN * 4;
    __hip_bfloat16* whT = (__hip_bfloat16*)ws;   ws += (size_t)RR * BB * HH * HD * NN * 2;
    unsigned* bmask = (unsigned*)ws;             ws += (size_t)RR * BB * NN * (NN / 32) * 4;

    // cooperative path (deterministic check each call)
    int mb = 0;
    hipError_t oe = hipOccupancyMaxActiveBlocksPerMultiprocessor(&mb, fused_kernel, 256, 0);
    if (oe == hipSuccess && mb >= 3) {
        void* args[] = { (void*)&H, (void*)&A, (void*)&W, (void*)&a_src, (void*)&a_dst,
                         (void*)&gamma, (void*)&beta, (void*)&out,
                         (void*)&es, (void*)&ed, (void*)&whT, (void*)&bmask,
                         (void*)&num, (void*)&den };
        if (hipLaunchCooperativeKernel((void*)fused_kernel, dim3(768), dim3(256),
                                       args, 0, stream) == hipSuccess)
            return;
    }

    // fallback: proven 3-kernel path (R12)
    prep_kernel<<<384 + RR * BB * NN * (NN / 32) / 256, 256, 0, stream>>>(
        H, A, W, a_src, a_dst, es, ed, whT, bmask);
    gat_attn_kernel<<<RR * BB * HH * 16 * 2, 256, 0, stream>>>(bmask, es, ed, whT, num, den);
    finalize_kernel<<<BB * NN / 4, 256, 0, stream>>>(H, num, den, gamma, beta, out);
}

// Round 14
// 65.528 us; speedup vs baseline: 1.0189x; 1.0189x over previous
//
#include <hip/hip_runtime.h>
#include <hip/hip_bf16.h>

// Problem constants (from reference setup_inputs)
#define RR 3
#define BB 2
#define NN 2048
#define DD 128
#define HH 4
#define HD 32
#define LEAKY 0.2f
#define LN_EPS 1e-5f
#define LOG2E 1.4426950408889634f

using f32x4  = __attribute__((ext_vector_type(4))) float;
using bf16x8 = __attribute__((ext_vector_type(8))) short;

__device__ __forceinline__ void gload_lds16(const void* g, void* l) {
    __builtin_amdgcn_global_load_lds(
        (const __attribute__((address_space(1))) unsigned*)g,
        (__attribute__((address_space(3))) unsigned*)l, 16, 0, 0);
}
__device__ __forceinline__ void gload_lds4(const void* g, void* l) {
    __builtin_amdgcn_global_load_lds(
        (const __attribute__((address_space(1))) unsigned*)g,
        (__attribute__((address_space(3))) unsigned*)l, 4, 0, 0);
}
__device__ __forceinline__ unsigned short bfb(float x) {
    return __builtin_bit_cast(unsigned short, __float2bfloat16(x));
}

// ---------------------------------------------------------------------------
// Bitmask layout (ballot-native): per row (2048 j): 8 chunks of 256 j;
// per chunk 8 words [q][half]; word bit i <-> j = chunk*256 + half*128 + 4i + q.
// Consumer (gat): bit (c>>2) of (word[c&3] >> (jc*8 + kg*2)).
// ---------------------------------------------------------------------------

// ---------------------------------------------------------------------------
// Kernel 1: fused prep. grid = 384 + 3072 blocks, 256 threads, NO LDS.
//  - bid<384: wh role (MFMA Wh^T + es/ed).
//  - bid>=384: ballot compact role. NEW: all 8 int4 loads issued into a
//    register array BEFORE any ballot (8KB/wave guaranteed in flight), and
//    the 8 masked 32B stores replaced by per-lane word capture + ONE
//    coalesced 256B store per row (identical bm indexing).
// ---------------------------------------------------------------------------
__global__ __launch_bounds__(256) void prep_kernel(
    const float* __restrict__ H, const int* __restrict__ A,
    const float* __restrict__ W,
    const float* __restrict__ a_src, const float* __restrict__ a_dst,
    float* __restrict__ es, float* __restrict__ ed,
    __hip_bfloat16* __restrict__ whT, unsigned* __restrict__ bm)
{
    const int bid = blockIdx.x;
    const int t = threadIdx.x;

    if (bid >= 384) {
        // ---- ballot compact role: wave handles one A row (2048 ints) ----
        const int cb = bid - 384;                       // 0..3071
        const long crow = (long)cb * 4 + (t >> 6);      // A row 0..12287
        const int lane = t & 63;
        const int4* Ap = (const int4*)A + crow * 512 + lane;

        // phase 1: issue ALL 8 loads (8KB in flight per wave)
        int4 v[8];
#pragma unroll
        for (int e = 0; e < 8; ++e) v[e] = Ap[e * 64];

        // phase 2: ballots; lane l captures word (e,q,half)=(l>>3,(l>>1)&3,l&1)
        const int sel_e = lane >> 3;
        const int sel_q = (lane >> 1) & 3;
        const int sel_h = lane & 1;
        unsigned word = 0;
#pragma unroll
        for (int e = 0; e < 8; ++e) {
            const unsigned long long B0 = __ballot(v[e].x != 0);
            const unsigned long long B1 = __ballot(v[e].y != 0);
            const unsigned long long B2 = __ballot(v[e].z != 0);
            const unsigned long long B3 = __ballot(v[e].w != 0);
            if (sel_e == e) {
                const unsigned long long Bq =
                    (sel_q == 3) ? B3 : (sel_q == 2) ? B2 : (sel_q == 1) ? B1 : B0;
                word = sel_h ? (unsigned)(Bq >> 32) : (unsigned)Bq;
            }
        }
        // one coalesced 256B store per wave-row
        bm[crow * 64 + lane] = word;
        return;
    }

    // ---- wh role ----
    const int rbh = bid >> 4;          // (r*BB+b)*HH+h
    const int nch = bid & 15;          // 128-col chunk
    const int h = rbh & 3;
    const int b = (rbh >> 2) & 1;
    const int r = rbh >> 3;
    const int wi = r * HH + h;
    const int w  = t >> 6;
    const int l  = t & 63;
    const int lr = l & 15;
    const int lg = l >> 4;

    const float* Wp = W + (long)wi * DD * HD;
    bf16x8 afr[2][4];
#pragma unroll
    for (int mt = 0; mt < 2; ++mt)
#pragma unroll
        for (int kt = 0; kt < 4; ++kt)
#pragma unroll
            for (int e = 0; e < 8; ++e)
                afr[mt][kt][e] = (short)bfb(Wp[(kt * 32 + lg * 8 + e) * HD + mt * 16 + lr]);

    float av[2][4], dv[2][4];
#pragma unroll
    for (int mt = 0; mt < 2; ++mt)
#pragma unroll
        for (int reg = 0; reg < 4; ++reg) {
            const int f = mt * 16 + lg * 4 + reg;
            av[mt][reg] = a_src[wi * HD + f] * LOG2E;
            dv[mt][reg] = a_dst[wi * HD + f] * LOG2E;
        }

#pragma unroll
    for (int nt = 0; nt < 2; ++nt) {
        const int ncol = nch * 128 + w * 32 + nt * 16 + lr;
        const float4* hrow4 = (const float4*)(H + ((long)b * NN + ncol) * DD);
        f32x4 acc0 = {0.f, 0.f, 0.f, 0.f};
        f32x4 acc1 = {0.f, 0.f, 0.f, 0.f};
#pragma unroll
        for (int kt = 0; kt < 4; ++kt) {
            float4 h0 = hrow4[kt * 8 + lg * 2];
            float4 h1 = hrow4[kt * 8 + lg * 2 + 1];
            bf16x8 bfr;
            bfr[0] = (short)bfb(h0.x); bfr[1] = (short)bfb(h0.y);
            bfr[2] = (short)bfb(h0.z); bfr[3] = (short)bfb(h0.w);
            bfr[4] = (short)bfb(h1.x); bfr[5] = (short)bfb(h1.y);
            bfr[6] = (short)bfb(h1.z); bfr[7] = (short)bfb(h1.w);
            acc0 = __builtin_amdgcn_mfma_f32_16x16x32_bf16(afr[0][kt], bfr, acc0, 0, 0, 0);
            acc1 = __builtin_amdgcn_mfma_f32_16x16x32_bf16(afr[1][kt], bfr, acc1, 0, 0, 0);
        }
        float s = 0.f, d = 0.f;
#pragma unroll
        for (int reg = 0; reg < 4; ++reg) {
            const int f0 = lg * 4 + reg;
            const int f1 = 16 + lg * 4 + reg;
            whT[((long)rbh * HD + f0) * NN + ncol] = __float2bfloat16(acc0[reg]);
            whT[((long)rbh * HD + f1) * NN + ncol] = __float2bfloat16(acc1[reg]);
            s = fmaf(acc0[reg], av[0][reg], s);
            s = fmaf(acc1[reg], av[1][reg], s);
            d = fmaf(acc0[reg], dv[0][reg], d);
            d = fmaf(acc1[reg], dv[1][reg], d);
        }
        s += __shfl_xor(s, 16); s += __shfl_xor(s, 32);
        d += __shfl_xor(d, 16); d += __shfl_xor(d, 32);
        if (l < 16) {
            es[(long)rbh * NN + ncol] = s;
            ed[(long)rbh * NN + ncol] = d;
        }
    }
}

// ---------------------------------------------------------------------------
// Kernel 2: fused masked softmax + MFMA aggregation (R12 structure + T5
// setprio around MFMA clusters). grid = 768 blocks (XCD swizzled).
// ---------------------------------------------------------------------------
__global__ __launch_bounds__(256, 3) void gat_attn_kernel(
    const unsigned* __restrict__ bm, const float* __restrict__ es,
    const float* __restrict__ ed, const __hip_bfloat16* __restrict__ whT,
    unsigned* __restrict__ num, float* __restrict__ den)
{
    const int lg = ((int)blockIdx.x % 8) * 96 + (int)blockIdx.x / 8;
    const int jh = lg & 1;
    const int it = (lg >> 1) & 15;
    const int h  = (lg >> 5) & 3;
    const int b  = (lg >> 7) & 1;
    const int r  = lg >> 8;
    const int i0 = it << 7;
    const int tid = threadIdx.x;
    const int w = tid >> 6;
    const int l = tid & 63;
    const int row = l & 15;
    const int kg  = l >> 4;
    const int f31 = l & 31;
    const int kgr = l >> 5;

    __shared__ __align__(16) short    whs[2][4][4][32][8];
    __shared__ __align__(16) unsigned bms[2][4][128];
    __shared__ __align__(16) float    eds[2][4][32];
    __shared__ float red[4];

    const int rbh = (r * BB + b) * HH + h;
    const long rbNN = (long)(r * BB + b) * NN;
    const __hip_bfloat16* whTr = whT + (long)rbh * HD * NN;
    const float* edr = ed + (long)rbh * NN;
    const int jbase = jh * (NN / 2);

#define STAGE(s, nb) do {                                                           \
        const int j0s = jbase + (s) * 128;                                          \
        const int S_ = jh * 8 + (s);                                                \
        const int woff_ = (S_ >> 1) * 8 + (S_ & 1) + w * 2;                         \
        gload_lds16(whTr + (long)f31 * NN + j0s + w * 32 + kgr * 8,                 \
                    &whs[nb][w][0][0][0]);                                          \
        gload_lds16(whTr + (long)f31 * NN + j0s + w * 32 + (2 + kgr) * 8,           \
                    &whs[nb][w][2][0][0]);                                          \
        gload_lds4(bm + (rbNN + i0 + l) * 64 + woff_, &bms[nb][w][0]);              \
        gload_lds4(bm + (rbNN + i0 + 64 + l) * 64 + woff_, &bms[nb][w][64]);        \
        if (l < 32) gload_lds4(edr + j0s + w * 32 + l, &eds[nb][w][0]);             \
    } while (0)

    STAGE(0, 0);

    // block-wide max of ed (upper bound; cancels exactly in num/den)
    float4 m0 = ((const float4*)edr)[tid * 2];
    float4 m1 = ((const float4*)edr)[tid * 2 + 1];
    float mm = fmaxf(fmaxf(fmaxf(m0.x, m0.y), fmaxf(m0.z, m0.w)),
                     fmaxf(fmaxf(m1.x, m1.y), fmaxf(m1.z, m1.w)));
#pragma unroll
    for (int d = 1; d < 64; d <<= 1) mm = fmaxf(mm, __shfl_xor(mm, d));
    if (l == 0) red[w] = mm;
    __syncthreads();
    const float medf = fmaxf(fmaxf(red[0], red[1]), fmaxf(red[2], red[3]));

    const float esvA = es[(long)rbh * NN + i0 + w * 16 + row];
    const float esvB = es[(long)rbh * NN + i0 + 64 + w * 16 + row];
    const float xA = esvA + medf, xB = esvB + medf;
    const float MA = fmaxf(xA, LEAKY * xA), MB = fmaxf(xB, LEAKY * xB);
    const float uA = esvA - MA, vA = fmaf(LEAKY, esvA, -MA);
    const float uB = esvB - MB, vB = fmaf(LEAKY, esvB, -MB);

    f32x4 acc0A = {0,0,0,0}, acc1A = {0,0,0,0}, accDA = {0,0,0,0};
    f32x4 acc0B = {0,0,0,0}, acc1B = {0,0,0,0}, accDB = {0,0,0,0};
    bf16x8 ones;
#pragma unroll
    for (int i = 0; i < 8; ++i) ones[i] = (short)0x3F80;

    const int kk = kg * 2;
    const int rAi = w * 16 + row, rBi = 64 + w * 16 + row;

    for (int s = 0; s < 8; ++s) {
        const int cb = s & 1, nb = cb ^ 1;
        if (s < 7) {
            STAGE(s + 1, nb);
            asm volatile("s_waitcnt vmcnt(5)" ::: "memory");
        } else {
            asm volatile("s_waitcnt vmcnt(0)" ::: "memory");
        }
        __builtin_amdgcn_s_barrier();
        __builtin_amdgcn_sched_barrier(0);

        unsigned wA[4], wB[4];
#pragma unroll
        for (int q = 0; q < 4; ++q) {
            wA[q] = bms[cb][q][rAi];
            wB[q] = bms[cb][q][rBi];
        }

#pragma unroll
        for (int jc = 0; jc < 4; ++jc) {
            bf16x8 b0 = *(const bf16x8*)&whs[cb][jc][kg][row][0];
            bf16x8 b1 = *(const bf16x8*)&whs[cb][jc][kg][row + 16][0];
            float4 e0 = *(const float4*)&eds[cb][jc][kg * 8];
            float4 e1 = *(const float4*)&eds[cb][jc][kg * 8 + 4];

            unsigned uAq[4], uBq[4];
#pragma unroll
            for (int q = 0; q < 4; ++q) {
                uAq[q] = wA[q] >> (jc * 8 + kk);
                uBq[q] = wB[q] >> (jc * 8 + kk);
            }

            float ev[8];
            ev[0] = e0.x; ev[1] = e0.y; ev[2] = e0.z; ev[3] = e0.w;
            ev[4] = e1.x; ev[5] = e1.y; ev[6] = e1.z; ev[7] = e1.w;

            bf16x8 pA, pB;
#pragma unroll
            for (int c = 0; c < 8; ++c) {
                float pa = __builtin_amdgcn_exp2f(
                    fmaxf(uA + ev[c], fmaf(LEAKY, ev[c], vA)));
                float pb = __builtin_amdgcn_exp2f(
                    fmaxf(uB + ev[c], fmaf(LEAKY, ev[c], vB)));
                const int ma = ((int)(uAq[c & 3] << (31 - (c >> 2)))) >> 31;
                const int mb = ((int)(uBq[c & 3] << (31 - (c >> 2)))) >> 31;
                pa = __uint_as_float(__float_as_uint(pa) & (unsigned)ma);
                pb = __uint_as_float(__float_as_uint(pb) & (unsigned)mb);
                __hip_bfloat16 ha = __float2bfloat16(pa);
                __hip_bfloat16 hb = __float2bfloat16(pb);
                pA[c] = __builtin_bit_cast(short, ha);
                pB[c] = __builtin_bit_cast(short, hb);
            }

            __builtin_amdgcn_s_setprio(1);
            acc0A = __builtin_amdgcn_mfma_f32_16x16x32_bf16(pA, b0, acc0A, 0, 0, 0);
            acc1A = __builtin_amdgcn_mfma_f32_16x16x32_bf16(pA, b1, acc1A, 0, 0, 0);
            accDA = __builtin_amdgcn_mfma_f32_16x16x32_bf16(pA, ones, accDA, 0, 0, 0);
            acc0B = __builtin_amdgcn_mfma_f32_16x16x32_bf16(pB, b0, acc0B, 0, 0, 0);
            acc1B = __builtin_amdgcn_mfma_f32_16x16x32_bf16(pB, b1, acc1B, 0, 0, 0);
            accDB = __builtin_amdgcn_mfma_f32_16x16x32_bf16(pB, ones, accDB, 0, 0, 0);
            __builtin_amdgcn_s_setprio(0);
        }
        __builtin_amdgcn_s_barrier();
        __builtin_amdgcn_sched_barrier(0);
    }
#undef STAGE

    const int fcol = l & 15;
    const int pr = r * 2 + jh;
#pragma unroll
    for (int reg = 0; reg < 4; ++reg) {
        const int orow = (l >> 4) * 4 + reg;
        const long roA = (long)pr * (BB * NN) + (long)b * NN + i0 + w * 16 + orow;
        const long roB = roA + 64;
        const unsigned wa = (unsigned)bfb(acc0A[reg]) | ((unsigned)bfb(acc1A[reg]) << 16);
        const unsigned wb_ = (unsigned)bfb(acc0B[reg]) | ((unsigned)bfb(acc1B[reg]) << 16);
        num[roA * 64 + h * 16 + fcol] = wa;
        num[roB * 64 + h * 16 + fcol] = wb_;
        if (fcol == 0) {
            den[roA * HH + h] = accDA[reg];
            den[roB * HH + h] = accDB[reg];
        }
    }
}

// ---------------------------------------------------------------------------
// Kernel 3: out = LayerNorm(H + mean_r (num_r / den_r)).  One wave per row;
// lane l owns cols c_lo = (l>>4)*32 + (l&15) and c_hi = c_lo + 16 (packed).
// ---------------------------------------------------------------------------
__global__ __launch_bounds__(256) void finalize_kernel(
    const float* __restrict__ H, const unsigned* __restrict__ num,
    const float* __restrict__ den,
    const float* __restrict__ gamma, const float* __restrict__ beta,
    float* __restrict__ out)
{
    const int w = threadIdx.x >> 6;
    const int l = threadIdx.x & 63;
    const long row = (long)blockIdx.x * 4 + w;
    const int hh = l >> 4, cc = l & 15;
    const int c_lo = hh * 32 + cc, c_hi = c_lo + 16;
    const float hx = H[row * DD + c_lo];
    const float hy = H[row * DD + c_hi];

    float ax = 0.f, ay = 0.f;
#pragma unroll
    for (int r = 0; r < RR; ++r) {
        float dsum = 0.f, nx = 0.f, ny = 0.f;
#pragma unroll
        for (int j = 0; j < 2; ++j) {
            const long ro = (long)(r * 2 + j) * (BB * NN) + row;
            dsum += den[ro * HH + hh];
            const unsigned wv = num[ro * 64 + l];
            nx += __uint_as_float(wv << 16);
            ny += __uint_as_float(wv & 0xffff0000u);
        }
        const float inv = (dsum > 0.f) ? 1.0f / dsum : 0.0f;
        ax = fmaf(nx, inv, ax);
        ay = fmaf(ny, inv, ay);
    }
    const float x0 = hx + ax * (1.0f / RR);
    const float x1 = hy + ay * (1.0f / RR);
    float s = x0 + x1, q = x0 * x0 + x1 * x1;
#pragma unroll
    for (int m = 1; m < 64; m <<= 1) {
        s += __shfl_xor(s, m);
        q += __shfl_xor(q, m);
    }
    const float mu  = s * (1.0f / DD);
    const float var = q * (1.0f / DD) - mu * mu;
    const float inv = rsqrtf(var + LN_EPS);
    out[row * DD + c_lo] = (x0 - mu) * inv * gamma[c_lo] + beta[c_lo];
    out[row * DD + c_hi] = (x1 - mu) * inv * gamma[c_hi] + beta[c_hi];
}

// ---------------------------------------------------------------------------
extern "C" void kernel_launch(void* const* d_in, const int* in_sizes, int n_in,
                              void* d_out, int out_size, void* d_ws, size_t ws_size,
                              hipStream_t stream)
{
    const float* H      = (const float*)d_in[0];
    const int*   A      = (const int*)d_in[1];
    const float* W      = (const float*)d_in[2];
    const float* a_src  = (const float*)d_in[3];
    const float* a_dst  = (const float*)d_in[4];
    const float* gamma  = (const float*)d_in[5];
    const float* beta   = (const float*)d_in[6];
    float* out = (float*)d_out;

    // workspace carve (~13.4 MB)
    char* ws = (char*)d_ws;
    unsigned* num = (unsigned*)ws;               ws += (size_t)RR * 2 * BB * NN * 64 * 4;
    float* den = (float*)ws;                     ws += (size_t)RR * 2 * BB * NN * HH * 4;
    float* es  = (float*)ws;                     ws += (size_t)RR * BB * HH * NN * 4;
    float* ed  = (float*)ws;                     ws += (size_t)RR * BB * HH * NN * 4;
    __hip_bfloat16* whT = (__hip_bfloat16*)ws;   ws += (size_t)RR * BB * HH * HD * NN * 2;
    unsigned* bmask = (unsigned*)ws;             ws += (size_t)RR * BB * NN * (NN / 32) * 4;

    prep_kernel<<<384 + RR * BB * NN * (NN / 32) / 256, 256, 0, stream>>>(
        H, A, W, a_src, a_dst, es, ed, whT, bmask);
    gat_attn_kernel<<<RR * BB * HH * 16 * 2, 256, 0, stream>>>(bmask, es, ed, whT, num, den);
    finalize_kernel<<<BB * NN / 4, 256, 0, stream>>>(H, num, den, gamma, beta, out);
}